// Round 4
// baseline (383.239 us; speedup 1.0000x reference)
//
#include <hip/hip_runtime.h>
#include <math.h>

#define B_  4
#define L_  2048
#define H_  8
#define D_  64
#define U_  40
#define HD  (H_*D_)   // 512

// ---------------------------------------------------------------------------
// Kernel 1: reproduce jax.random.randint(jax.random.key(42), (2048,40), 0, 2048)
// exactly, under jax_threefry_partitionable=True (default since JAX 0.4.30).
//
// randint splits the key: k1,k2 = split(key); with span=2048 the multiplier
// ((2^16 % 2048)^2 % 2048) is 0, so result = random_bits(k2) & 2047.
//   split (partitionable): child i = threefry2x32(key, (i>>32, i&0xffffffff)),
//     both output words -> k2 = tf((0,42), (0,1)).
//   random_bits (partitionable, 32-bit): element j
//     = tf(k2, (0,j)).bits1 ^ .bits2.
// The child-key hash is all-constant -> computed constexpr at compile time.
// ---------------------------------------------------------------------------
struct U2 { unsigned a, b; };

__host__ __device__ constexpr unsigned rotl32c(unsigned x, int r){
  return (x<<r)|(x>>(32-r));
}

__host__ __device__ constexpr U2 tf2x32(unsigned k0, unsigned k1,
                                        unsigned x0, unsigned x1)
{
  const unsigned k2 = k0 ^ k1 ^ 0x1BD11BDAu;
  const int rA[4] = {13,15,26,6};
  const int rB[4] = {17,29,16,24};
  x0 += k0; x1 += k1;
  for (int i=0;i<4;i++){ x0+=x1; x1=rotl32c(x1,rA[i]); x1^=x0; }
  x0 += k1; x1 += k2 + 1u;
  for (int i=0;i<4;i++){ x0+=x1; x1=rotl32c(x1,rB[i]); x1^=x0; }
  x0 += k2; x1 += k0 + 2u;
  for (int i=0;i<4;i++){ x0+=x1; x1=rotl32c(x1,rA[i]); x1^=x0; }
  x0 += k0; x1 += k1 + 3u;
  for (int i=0;i<4;i++){ x0+=x1; x1=rotl32c(x1,rB[i]); x1^=x0; }
  x0 += k1; x1 += k2 + 4u;
  for (int i=0;i<4;i++){ x0+=x1; x1=rotl32c(x1,rA[i]); x1^=x0; }
  x0 += k2; x1 += k0 + 5u;
  return U2{x0, x1};
}

__global__ __launch_bounds__(256) void idx_kernel(int* __restrict__ idx)
{
  unsigned j = blockIdx.x*256u + threadIdx.x;
  if (j >= 81920u) return;
  constexpr U2 K2 = tf2x32(0u, 42u, 0u, 1u);   // second child of split(key(42))
  U2 r = tf2x32(K2.a, K2.b, 0u, j);            // random_bits element j
  idx[j] = (int)((r.a ^ r.b) & 2047u);
}

// ---------------------------------------------------------------------------
// Kernel 2: sparsity measure M[b,h,l] = max_s(q.k_s) - sum_s(q.k_s)/2048
// One wave per (bh,l); lane s<40 computes one sampled dot via float4 loads.
// Grid swizzle g = lblk*32 + bh keeps each bh's K slab on one XCD's L2.
// ---------------------------------------------------------------------------
__global__ __launch_bounds__(256) void m_kernel(const float* __restrict__ q,
                                                const float* __restrict__ k,
                                                const int*   __restrict__ idx,
                                                float*       __restrict__ M)
{
  int g    = blockIdx.x;
  int bh   = g & 31;
  int l    = ((g >> 5) << 2) + (threadIdx.x >> 6);
  int lane = threadIdx.x & 63;
  int b = bh >> 3, h = bh & 7;
  const float4* qrow = (const float4*)(q + (size_t)(b*L_ + l)*HD + h*D_);
  float dot = 0.f;
  if (lane < U_) {
    int kidx = idx[l*U_ + lane];
    const float4* krow = (const float4*)(k + (size_t)(b*L_ + kidx)*HD + h*D_);
    #pragma unroll
    for (int t=0;t<16;t++){
      float4 a = qrow[t], bb = krow[t];
      dot += a.x*bb.x + a.y*bb.y + a.z*bb.z + a.w*bb.w;
    }
  }
  float vmax = (lane < U_) ? dot : -INFINITY;
  float vsum = (lane < U_) ? dot : 0.f;
  #pragma unroll
  for (int off=32; off; off>>=1){
    vmax  = fmaxf(vmax, __shfl_xor(vmax, off, 64));
    vsum += __shfl_xor(vsum, off, 64);
  }
  if (lane == 0) M[bh*L_ + l] = vmax - vsum * (1.0f/(float)L_);
}

// ---------------------------------------------------------------------------
// Kernel 3: top-40 indices per (b,h). One wave per bh, M in LDS, 40x argmax.
// Only the SET of indices matters for correctness.
// ---------------------------------------------------------------------------
__global__ __launch_bounds__(64) void topk_kernel(const float* __restrict__ M,
                                                  int* __restrict__ mtop)
{
  __shared__ float mv[L_];
  int bh = blockIdx.x;
  int lane = threadIdx.x;
  for (int i=0;i<32;i++) mv[lane + 64*i] = M[bh*L_ + lane + 64*i];
  __syncthreads();
  for (int it=0; it<U_; ++it){
    float best = -INFINITY; int bi = 0x7fffffff;
    for (int i=0;i<32;i++){
      float vv = mv[lane + 64*i];
      if (vv > best){ best = vv; bi = lane + 64*i; }
    }
    #pragma unroll
    for (int off=32; off; off>>=1){
      float ov = __shfl_xor(best, off, 64);
      int   oi = __shfl_xor(bi,   off, 64);
      if (ov > best || (ov == best && oi < bi)){ best = ov; bi = oi; }
    }
    if (lane == 0){ mtop[bh*U_ + it] = bi; mv[bi] = -INFINITY; }
    __syncthreads();
  }
}

// ---------------------------------------------------------------------------
// Kernel 4: V column sums (for mean). 512 blocks = 32 bh x 16 l-chunks,
// partial sums atomically added into vmean[bh*64+d] (zeroed by memset).
// ---------------------------------------------------------------------------
__global__ __launch_bounds__(256) void vmean_kernel(const float* __restrict__ v,
                                                    float* __restrict__ vmean)
{
  int g = blockIdx.x;
  int bh = g & 31, chunk = g >> 5;
  int b = bh >> 3, h = bh & 7;
  int w = threadIdx.x >> 6, lane = threadIdx.x & 63;
  int l0 = chunk*128 + w*32;
  float s = 0.f;
  for (int i=0;i<32;i++)
    s += v[(size_t)(b*L_ + l0 + i)*HD + h*D_ + lane];
  atomicAdd(&vmean[bh*D_ + lane], s);
}

// ---------------------------------------------------------------------------
// Kernel 5: out[b][l][h][:] = V_mean[b][h][:]  (sum * 1/2048), float4 stores.
// ---------------------------------------------------------------------------
__global__ __launch_bounds__(256) void init_kernel(const float* __restrict__ vmean,
                                                   float* __restrict__ out)
{
  int i = blockIdx.x*256 + threadIdx.x;   // float4 index, 0..1048575
  int d4 = i & 15;
  int h  = (i >> 4) & 7;
  int bl = i >> 7;                        // b*2048 + l
  int b  = bl >> 11;
  float4 vm = ((const float4*)(vmean + (b*H_ + h)*D_))[d4];
  const float sc = 1.0f/(float)L_;
  float4 o; o.x = vm.x*sc; o.y = vm.y*sc; o.z = vm.z*sc; o.w = vm.w*sc;
  ((float4*)out)[i] = o;
}

// ---------------------------------------------------------------------------
// Kernel 6: flash-style attention for the 40 selected rows per (b,h).
// Block = 256 thr (4 waves), each wave owns one u; 10 blocks per bh.
// K/V tiles of 128 rows staged in LDS; K XOR-swizzled per row to avoid the
// 64-float-stride bank conflict on the row-per-lane score reads.
// Online softmax (m,l running); lane owns output dim d=lane in the PV phase.
// ---------------------------------------------------------------------------
__global__ __launch_bounds__(256) void attn_kernel(const float* __restrict__ q,
                                                   const float* __restrict__ k,
                                                   const float* __restrict__ v,
                                                   const int*   __restrict__ mtop,
                                                   float*       __restrict__ out)
{
  __shared__ float Kt[128][64];
  __shared__ float Vt[128][64];
  __shared__ float ps[4][128];
  int g = blockIdx.x;
  int bh = g & 31, ublk = g >> 5;
  int b = bh >> 3, h = bh & 7;
  int w = threadIdx.x >> 6, lane = threadIdx.x & 63;
  int u = ublk*4 + w;
  int lstar = mtop[bh*U_ + u];
  const float4* qrow = (const float4*)(q + (size_t)(b*L_ + lstar)*HD + h*D_);
  float qreg[64];
  #pragma unroll
  for (int t=0;t<16;t++){
    float4 qq = qrow[t];
    qreg[4*t+0]=qq.x; qreg[4*t+1]=qq.y; qreg[4*t+2]=qq.z; qreg[4*t+3]=qq.w;
  }
  float m_run = -INFINITY, l_run = 0.f, acc = 0.f;
  for (int kt = 0; kt < L_; kt += 128){
    __syncthreads();   // previous tile's PV reads done before restaging
    #pragma unroll
    for (int c=0;c<8;c++){
      int flat = c*256 + threadIdx.x;
      int row = flat >> 4, col = flat & 15;
      const float4* ks = (const float4*)(k + (size_t)(b*L_ + kt + row)*HD + h*D_);
      const float4* vs = (const float4*)(v + (size_t)(b*L_ + kt + row)*HD + h*D_);
      ((float4*)Kt[row])[col ^ (row & 7)] = ks[col];
      ((float4*)Vt[row])[col]             = vs[col];
    }
    __syncthreads();
    // scores: lane owns tile rows lane and lane+64
    int r0 = lane, r1 = lane + 64;
    float s0 = 0.f, s1 = 0.f;
    #pragma unroll
    for (int t=0;t<16;t++){
      float4 a  = ((const float4*)Kt[r0])[t ^ (r0 & 7)];
      float4 c1 = ((const float4*)Kt[r1])[t ^ (r1 & 7)];
      s0 += a.x *qreg[4*t] + a.y *qreg[4*t+1] + a.z *qreg[4*t+2] + a.w *qreg[4*t+3];
      s1 += c1.x*qreg[4*t] + c1.y*qreg[4*t+1] + c1.z*qreg[4*t+2] + c1.w*qreg[4*t+3];
    }
    s0 *= 0.125f; s1 *= 0.125f;
    float tmax = fmaxf(s0, s1);
    #pragma unroll
    for (int off=32; off; off>>=1) tmax = fmaxf(tmax, __shfl_xor(tmax, off, 64));
    float m_new = fmaxf(m_run, tmax);
    float alpha = __expf(m_run - m_new);    // first tile: exp(-inf)=0
    float p0 = __expf(s0 - m_new);
    float p1 = __expf(s1 - m_new);
    float psum = p0 + p1;
    #pragma unroll
    for (int off=32; off; off>>=1) psum += __shfl_xor(psum, off, 64);
    l_run = l_run*alpha + psum;
    m_run = m_new;
    ps[w][lane] = p0; ps[w][lane+64] = p1;
    __syncthreads();
    // PV: lane owns output dim d=lane. Vt[j][lane] is 2-way bank aliasing (free).
    float add = 0.f;
    #pragma unroll
    for (int j4=0;j4<32;j4++){
      float4 pp = ((const float4*)ps[w])[j4];
      add += pp.x*Vt[4*j4+0][lane] + pp.y*Vt[4*j4+1][lane]
           + pp.z*Vt[4*j4+2][lane] + pp.w*Vt[4*j4+3][lane];
    }
    acc = acc*alpha + add;
  }
  out[(size_t)(b*L_ + lstar)*HD + h*D_ + lane] = acc / l_run;
}

// ---------------------------------------------------------------------------
extern "C" void kernel_launch(void* const* d_in, const int* in_sizes, int n_in,
                              void* d_out, int out_size, void* d_ws, size_t ws_size,
                              hipStream_t stream)
{
  const float* q = (const float*)d_in[0];
  const float* k = (const float*)d_in[1];
  const float* v = (const float*)d_in[2];
  float* out = (float*)d_out;

  // workspace layout (bytes): idx[81920 i32] @0, M[65536 f32] @327680,
  // mtop[1280 i32] @589824, vmean[2048 f32] @594944. Total 603136 B.
  int*   idx   = (int*)d_ws;
  float* M     = (float*)((char*)d_ws + 327680);
  int*   mtop  = (int*)((char*)d_ws + 589824);
  float* vmean = (float*)((char*)d_ws + 594944);

  hipMemsetAsync(vmean, 0, 2048*sizeof(float), stream);
  idx_kernel  <<<320,   256, 0, stream>>>(idx);
  m_kernel    <<<16384, 256, 0, stream>>>(q, k, idx, M);
  topk_kernel <<<32,     64, 0, stream>>>(M, mtop);
  vmean_kernel<<<512,   256, 0, stream>>>(v, vmean);
  init_kernel <<<4096,  256, 0, stream>>>(vmean, out);
  attn_kernel <<<320,   256, 0, stream>>>(q, k, v, mtop, out);
}

// Round 5
// 265.740 us; speedup vs baseline: 1.4422x; 1.4422x over previous
//
#include <hip/hip_runtime.h>
#include <math.h>

#define B_  4
#define L_  2048
#define H_  8
#define D_  64
#define U_  40
#define HD  (H_*D_)   // 512
#define KC_ 4         // K-dimension split factor for attention
#define KCL (L_/KC_)  // 512 keys per chunk

// ---------------------------------------------------------------------------
// Kernel 1: reproduce jax.random.randint(jax.random.key(42), (2048,40), 0, 2048)
// exactly, under jax_threefry_partitionable=True (default since JAX 0.4.30).
// randint splits the key; span=2048 -> multiplier term is 0, so
// result = random_bits(k2) & 2047, k2 = tf((0,42),(0,1)) (constexpr),
// element j = tf(k2,(0,j)).b1 ^ .b2.   [verified: round-4 pass]
// ---------------------------------------------------------------------------
struct U2 { unsigned a, b; };

__host__ __device__ constexpr unsigned rotl32c(unsigned x, int r){
  return (x<<r)|(x>>(32-r));
}

__host__ __device__ constexpr U2 tf2x32(unsigned k0, unsigned k1,
                                        unsigned x0, unsigned x1)
{
  const unsigned k2 = k0 ^ k1 ^ 0x1BD11BDAu;
  const int rA[4] = {13,15,26,6};
  const int rB[4] = {17,29,16,24};
  x0 += k0; x1 += k1;
  for (int i=0;i<4;i++){ x0+=x1; x1=rotl32c(x1,rA[i]); x1^=x0; }
  x0 += k1; x1 += k2 + 1u;
  for (int i=0;i<4;i++){ x0+=x1; x1=rotl32c(x1,rB[i]); x1^=x0; }
  x0 += k2; x1 += k0 + 2u;
  for (int i=0;i<4;i++){ x0+=x1; x1=rotl32c(x1,rA[i]); x1^=x0; }
  x0 += k0; x1 += k1 + 3u;
  for (int i=0;i<4;i++){ x0+=x1; x1=rotl32c(x1,rB[i]); x1^=x0; }
  x0 += k1; x1 += k2 + 4u;
  for (int i=0;i<4;i++){ x0+=x1; x1=rotl32c(x1,rA[i]); x1^=x0; }
  x0 += k2; x1 += k0 + 5u;
  return U2{x0, x1};
}

__global__ __launch_bounds__(256) void idx_kernel(int* __restrict__ idx)
{
  unsigned j = blockIdx.x*256u + threadIdx.x;
  if (j >= 81920u) return;
  constexpr U2 K2 = tf2x32(0u, 42u, 0u, 1u);   // second child of split(key(42))
  U2 r = tf2x32(K2.a, K2.b, 0u, j);            // random_bits element j
  idx[j] = (int)((r.a ^ r.b) & 2047u);
}

// ---------------------------------------------------------------------------
// Kernel 2: M[b,h,l] = max_s(q.k_s) - sum_s(q.k_s)/2048 over 40 sampled keys.
// One wave per (bh,l). Layout: 8 sample-groups x 8 lanes; each group reads a
// full 256 B K row COALESCED (2 float4/lane), so the wave's unavoidable
// 40-row x 256 B traffic moves in 10 VMEM instrs instead of a 40-way gather
// (round-4: 182 us, 10% VALU, 1.3% HBM = transaction-latency-bound).
// Dot = 8-float/lane partial + xor{1,2,4} butterfly; cross-group xor{8,16,32}.
// ---------------------------------------------------------------------------
__global__ __launch_bounds__(256) void m_kernel(const float* __restrict__ q,
                                                const float* __restrict__ k,
                                                const int*   __restrict__ idx,
                                                float*       __restrict__ M)
{
  int g    = blockIdx.x;
  int bh   = g & 31;
  int l    = ((g >> 5) << 2) + (threadIdx.x >> 6);
  int lane = threadIdx.x & 63;
  int b = bh >> 3, h = bh & 7;
  int grp  = lane >> 3;        // sample subgroup 0..7
  int l8   = lane & 7;         // owns floats [l8*8, l8*8+8) of the row
  const float* qrow = q + (size_t)(b*L_ + l)*HD + h*D_;
  float4 q0 = *(const float4*)(qrow + l8*8);
  float4 q1 = *(const float4*)(qrow + l8*8 + 4);
  int myidx = (lane < U_) ? idx[l*U_ + lane] : 0;
  const float* kbase = k + (size_t)b*L_*HD + h*D_;
  float vmax = -INFINITY, vsum = 0.f;
  #pragma unroll
  for (int t=0;t<5;t++){
    int s = t*8 + grp;
    int kidx = __shfl(myidx, s, 64);
    const float* krow = kbase + (size_t)kidx*HD;
    float4 k0 = *(const float4*)(krow + l8*8);
    float4 k1 = *(const float4*)(krow + l8*8 + 4);
    float p = q0.x*k0.x + q0.y*k0.y + q0.z*k0.z + q0.w*k0.w
            + q1.x*k1.x + q1.y*k1.y + q1.z*k1.z + q1.w*k1.w;
    p += __shfl_xor(p, 1, 64);
    p += __shfl_xor(p, 2, 64);
    p += __shfl_xor(p, 4, 64);   // all 8 lanes of grp now hold dot(sample s)
    vmax = fmaxf(vmax, p);
    vsum += p;
  }
  vmax = fmaxf(vmax, __shfl_xor(vmax, 8, 64));
  vmax = fmaxf(vmax, __shfl_xor(vmax,16, 64));
  vmax = fmaxf(vmax, __shfl_xor(vmax,32, 64));
  vsum += __shfl_xor(vsum, 8, 64);
  vsum += __shfl_xor(vsum,16, 64);
  vsum += __shfl_xor(vsum,32, 64);
  if (lane == 0) M[bh*L_ + l] = vmax - vsum * (1.0f/(float)L_);
}

// ---------------------------------------------------------------------------
// Kernel 3: top-40 indices per (b,h). One wave per bh, M in LDS, 40x argmax.
// ---------------------------------------------------------------------------
__global__ __launch_bounds__(64) void topk_kernel(const float* __restrict__ M,
                                                  int* __restrict__ mtop)
{
  __shared__ float mv[L_];
  int bh = blockIdx.x;
  int lane = threadIdx.x;
  for (int i=0;i<32;i++) mv[lane + 64*i] = M[bh*L_ + lane + 64*i];
  __syncthreads();
  for (int it=0; it<U_; ++it){
    float best = -INFINITY; int bi = 0x7fffffff;
    for (int i=0;i<32;i++){
      float vv = mv[lane + 64*i];
      if (vv > best){ best = vv; bi = lane + 64*i; }
    }
    #pragma unroll
    for (int off=32; off; off>>=1){
      float ov = __shfl_xor(best, off, 64);
      int   oi = __shfl_xor(bi,   off, 64);
      if (ov > best || (ov == best && oi < bi)){ best = ov; bi = oi; }
    }
    if (lane == 0){ mtop[bh*U_ + it] = bi; mv[bi] = -INFINITY; }
    __syncthreads();
  }
}

// ---------------------------------------------------------------------------
// Kernel 4: V column sums (for mean), atomically accumulated into vmean.
// ---------------------------------------------------------------------------
__global__ __launch_bounds__(256) void vmean_kernel(const float* __restrict__ v,
                                                    float* __restrict__ vmean)
{
  int g = blockIdx.x;
  int bh = g & 31, chunk = g >> 5;
  int b = bh >> 3, h = bh & 7;
  int w = threadIdx.x >> 6, lane = threadIdx.x & 63;
  int l0 = chunk*128 + w*32;
  float s = 0.f;
  for (int i=0;i<32;i++)
    s += v[(size_t)(b*L_ + l0 + i)*HD + h*D_ + lane];
  atomicAdd(&vmean[bh*D_ + lane], s);
}

// ---------------------------------------------------------------------------
// Kernel 5: out[b][l][h][:] = V_mean[b][h][:]  (sum * 1/2048), float4 stores.
// ---------------------------------------------------------------------------
__global__ __launch_bounds__(256) void init_kernel(const float* __restrict__ vmean,
                                                   float* __restrict__ out)
{
  int i = blockIdx.x*256 + threadIdx.x;   // float4 index, 0..1048575
  int d4 = i & 15;
  int h  = (i >> 4) & 7;
  int bl = i >> 7;
  int b  = bl >> 11;
  float4 vm = ((const float4*)(vmean + (b*H_ + h)*D_))[d4];
  const float sc = 1.0f/(float)L_;
  float4 o; o.x = vm.x*sc; o.y = vm.y*sc; o.z = vm.z*sc; o.w = vm.w*sc;
  ((float4*)out)[i] = o;
}

// ---------------------------------------------------------------------------
// Kernel 6: flash attention over the 40 selected rows, K-SPLIT by 4 chunks
// (round-4 attn was grid-starved: 320 blocks = 1.25 blocks/CU). Grid = 1280:
// g -> bh (32) x ug (10) x kc (4). Block = 4 waves, wave w owns u = ug*4+w,
// processes keys [kc*512, kc*512+512) as 4 LDS tiles of 128, writes an
// UNNORMALIZED partial (m_run, l_run, acc[64]) to workspace.
// ---------------------------------------------------------------------------
__global__ __launch_bounds__(256) void attn_kernel(const float* __restrict__ q,
                                                   const float* __restrict__ k,
                                                   const float* __restrict__ v,
                                                   const int*   __restrict__ mtop,
                                                   float* __restrict__ pm,
                                                   float* __restrict__ pl,
                                                   float* __restrict__ pacc)
{
  __shared__ float Kt[128][64];
  __shared__ float Vt[128][64];
  __shared__ float ps[4][128];
  int g = blockIdx.x;                  // 0..1279
  int bh = g & 31;
  int t5 = g >> 5;                     // 0..39
  int kc = t5 & 3;
  int ug = t5 >> 2;                    // 0..9
  int b = bh >> 3, h = bh & 7;
  int w = threadIdx.x >> 6, lane = threadIdx.x & 63;
  int u = ug*4 + w;
  int lstar = mtop[bh*U_ + u];
  const float4* qrow = (const float4*)(q + (size_t)(b*L_ + lstar)*HD + h*D_);
  float qreg[64];
  #pragma unroll
  for (int t=0;t<16;t++){
    float4 qq = qrow[t];
    qreg[4*t+0]=qq.x; qreg[4*t+1]=qq.y; qreg[4*t+2]=qq.z; qreg[4*t+3]=qq.w;
  }
  float m_run = -INFINITY, l_run = 0.f, acc = 0.f;
  for (int kt = kc*KCL; kt < kc*KCL + KCL; kt += 128){
    __syncthreads();
    #pragma unroll
    for (int c=0;c<8;c++){
      int flat = c*256 + threadIdx.x;
      int row = flat >> 4, col = flat & 15;
      const float4* ks = (const float4*)(k + (size_t)(b*L_ + kt + row)*HD + h*D_);
      const float4* vs = (const float4*)(v + (size_t)(b*L_ + kt + row)*HD + h*D_);
      ((float4*)Kt[row])[col ^ (row & 7)] = ks[col];
      ((float4*)Vt[row])[col]             = vs[col];
    }
    __syncthreads();
    int r0 = lane, r1 = lane + 64;
    float s0 = 0.f, s1 = 0.f;
    #pragma unroll
    for (int t=0;t<16;t++){
      float4 a  = ((const float4*)Kt[r0])[t ^ (r0 & 7)];
      float4 c1 = ((const float4*)Kt[r1])[t ^ (r1 & 7)];
      s0 += a.x *qreg[4*t] + a.y *qreg[4*t+1] + a.z *qreg[4*t+2] + a.w *qreg[4*t+3];
      s1 += c1.x*qreg[4*t] + c1.y*qreg[4*t+1] + c1.z*qreg[4*t+2] + c1.w*qreg[4*t+3];
    }
    s0 *= 0.125f; s1 *= 0.125f;
    float tmax = fmaxf(s0, s1);
    #pragma unroll
    for (int off=32; off; off>>=1) tmax = fmaxf(tmax, __shfl_xor(tmax, off, 64));
    float m_new = fmaxf(m_run, tmax);
    float alpha = __expf(m_run - m_new);
    float p0 = __expf(s0 - m_new);
    float p1 = __expf(s1 - m_new);
    float psum = p0 + p1;
    #pragma unroll
    for (int off=32; off; off>>=1) psum += __shfl_xor(psum, off, 64);
    l_run = l_run*alpha + psum;
    m_run = m_new;
    ps[w][lane] = p0; ps[w][lane+64] = p1;
    __syncthreads();
    float add = 0.f;
    #pragma unroll
    for (int j4=0;j4<32;j4++){
      float4 pp = ((const float4*)ps[w])[j4];
      add += pp.x*Vt[4*j4+0][lane] + pp.y*Vt[4*j4+1][lane]
           + pp.z*Vt[4*j4+2][lane] + pp.w*Vt[4*j4+3][lane];
    }
    acc = acc*alpha + add;
  }
  int gu = bh*U_ + u;                  // 0..1279
  int pid = gu*KC_ + kc;
  if (lane == 0){ pm[pid] = m_run; pl[pid] = l_run; }
  pacc[(size_t)pid*64 + lane] = acc;
}

// ---------------------------------------------------------------------------
// Kernel 7: merge the 4 K-chunk partials per (bh,u) and write selected rows.
// One wave per (bh,u); lane = output dim d.
// ---------------------------------------------------------------------------
__global__ __launch_bounds__(256) void combine_kernel(const int* __restrict__ mtop,
                                                      const float* __restrict__ pm,
                                                      const float* __restrict__ pl,
                                                      const float* __restrict__ pacc,
                                                      float* __restrict__ out)
{
  int gu = blockIdx.x*4 + (threadIdx.x >> 6);  // 0..1279
  int lane = threadIdx.x & 63;
  int bh = gu / U_, u = gu - bh*U_;
  float m0 = pm[gu*KC_+0], m1 = pm[gu*KC_+1], m2 = pm[gu*KC_+2], m3 = pm[gu*KC_+3];
  float Mx = fmaxf(fmaxf(m0,m1), fmaxf(m2,m3));
  float e0 = __expf(m0-Mx), e1 = __expf(m1-Mx), e2 = __expf(m2-Mx), e3 = __expf(m3-Mx);
  float Ls = pl[gu*KC_+0]*e0 + pl[gu*KC_+1]*e1 + pl[gu*KC_+2]*e2 + pl[gu*KC_+3]*e3;
  float a  = pacc[(size_t)(gu*KC_+0)*64+lane]*e0 + pacc[(size_t)(gu*KC_+1)*64+lane]*e1
           + pacc[(size_t)(gu*KC_+2)*64+lane]*e2 + pacc[(size_t)(gu*KC_+3)*64+lane]*e3;
  int b = bh >> 3, h = bh & 7;
  int lstar = mtop[bh*U_ + u];
  out[(size_t)(b*L_ + lstar)*HD + h*D_ + lane] = a / Ls;
}

// ---------------------------------------------------------------------------
extern "C" void kernel_launch(void* const* d_in, const int* in_sizes, int n_in,
                              void* d_out, int out_size, void* d_ws, size_t ws_size,
                              hipStream_t stream)
{
  const float* q = (const float*)d_in[0];
  const float* k = (const float*)d_in[1];
  const float* v = (const float*)d_in[2];
  float* out = (float*)d_out;

  // workspace layout (bytes):
  //   idx   [81920 i32]        @ 0
  //   M     [65536 f32]        @ 327680
  //   mtop  [1280 i32]         @ 589824
  //   vmean [2048 f32]         @ 594944
  //   pm    [5120 f32]         @ 603136
  //   pl    [5120 f32]         @ 623616
  //   pacc  [327680 f32]       @ 644096   (total 1954816 B)
  int*   idx   = (int*)d_ws;
  float* M     = (float*)((char*)d_ws + 327680);
  int*   mtop  = (int*)((char*)d_ws + 589824);
  float* vmean = (float*)((char*)d_ws + 594944);
  float* pm    = (float*)((char*)d_ws + 603136);
  float* pl    = (float*)((char*)d_ws + 623616);
  float* pacc  = (float*)((char*)d_ws + 644096);

  hipMemsetAsync(vmean, 0, 2048*sizeof(float), stream);
  idx_kernel    <<<320,   256, 0, stream>>>(idx);
  m_kernel      <<<16384, 256, 0, stream>>>(q, k, idx, M);
  topk_kernel   <<<32,     64, 0, stream>>>(M, mtop);
  vmean_kernel  <<<512,   256, 0, stream>>>(v, vmean);
  init_kernel   <<<4096,  256, 0, stream>>>(vmean, out);
  attn_kernel   <<<1280,  256, 0, stream>>>(q, k, v, mtop, pm, pl, pacc);
  combine_kernel<<<320,   256, 0, stream>>>(mtop, pm, pl, pacc, out);
}

// Round 6
// 237.542 us; speedup vs baseline: 1.6133x; 1.1187x over previous
//
#include <hip/hip_runtime.h>
#include <math.h>

#define B_  4
#define L_  2048
#define H_  8
#define D_  64
#define U_  40
#define HD  (H_*D_)   // 512

// ws offsets (bytes)
#define OFF_M     0          // 65536 f32
#define OFF_MTOP  262144     // 1280 i32
#define OFF_VMEAN 267264     // 2048 f32
#define OFF_PM    275456     // up to 20480 f32 (KC=16)
#define OFF_PL    357376     // up to 20480 f32
#define OFF_PACC  439296     // up to 1280*16*64 f32 = 5242880 B
#define WS_NEED_KC16 (OFF_PACC + 1280*16*64*4)
#define WS_NEED_KC4  (OFF_PACC + 1280*4*64*4)

// ---------------------------------------------------------------------------
// threefry2x32 (jax partitionable stream) — verified bit-exact round 4.
// randint(key(42),(2048,40),0,2048) = tf(k2,(0,j)).b1 ^ .b2 & 2047 where
// k2 = tf((0,42),(0,1)) (second child of split), j = row*40+col.
// ---------------------------------------------------------------------------
struct U2 { unsigned a, b; };

__host__ __device__ constexpr unsigned rotl32c(unsigned x, int r){
  return (x<<r)|(x>>(32-r));
}

__host__ __device__ constexpr U2 tf2x32(unsigned k0, unsigned k1,
                                        unsigned x0, unsigned x1)
{
  const unsigned k2 = k0 ^ k1 ^ 0x1BD11BDAu;
  const int rA[4] = {13,15,26,6};
  const int rB[4] = {17,29,16,24};
  x0 += k0; x1 += k1;
  for (int i=0;i<4;i++){ x0+=x1; x1=rotl32c(x1,rA[i]); x1^=x0; }
  x0 += k1; x1 += k2 + 1u;
  for (int i=0;i<4;i++){ x0+=x1; x1=rotl32c(x1,rB[i]); x1^=x0; }
  x0 += k2; x1 += k0 + 2u;
  for (int i=0;i<4;i++){ x0+=x1; x1=rotl32c(x1,rA[i]); x1^=x0; }
  x0 += k0; x1 += k1 + 3u;
  for (int i=0;i<4;i++){ x0+=x1; x1=rotl32c(x1,rB[i]); x1^=x0; }
  x0 += k1; x1 += k2 + 4u;
  for (int i=0;i<4;i++){ x0+=x1; x1=rotl32c(x1,rA[i]); x1^=x0; }
  x0 += k2; x1 += k0 + 5u;
  return U2{x0, x1};
}

// ---------------------------------------------------------------------------
// Kernel 1: M[b,h,l] = max_s(q.k_s) - sum_s(q.k_s)/2048 over 40 sampled keys.
// One wave per (bh,l); 8 sample-groups x 8 lanes, coalesced 256 B row reads.
// idx computed INLINE (threefry ~120 VALU cy/wave — cheaper than a dispatch).
// Grid: 512 consecutive blocks per bh so each XCD's L2 holds ONE 512 KB
// K slab at a time (r5's bh=g&31 interleave put all 16 MB on every XCD).
// ---------------------------------------------------------------------------
__global__ __launch_bounds__(256) void m_kernel(const float* __restrict__ q,
                                                const float* __restrict__ k,
                                                float*       __restrict__ M)
{
  int g    = blockIdx.x;        // 16384
  int bh   = g >> 9;            // 0..31, 512 consecutive blocks each
  int lblk = g & 511;
  int w    = threadIdx.x >> 6, lane = threadIdx.x & 63;
  int l    = lblk*4 + w;
  int b = bh >> 3, h = bh & 7;
  int grp  = lane >> 3;         // sample subgroup 0..7
  int l8   = lane & 7;          // owns floats [l8*8, l8*8+8) of the row
  const float* qrow = q + (size_t)(b*L_ + l)*HD + h*D_;
  float4 q0 = *(const float4*)(qrow + l8*8);
  float4 q1 = *(const float4*)(qrow + l8*8 + 4);
  constexpr U2 K2 = tf2x32(0u, 42u, 0u, 1u);
  int myidx = 0;
  if (lane < U_){
    U2 r = tf2x32(K2.a, K2.b, 0u, (unsigned)(l*U_ + lane));
    myidx = (int)((r.a ^ r.b) & 2047u);
  }
  const float* kbase = k + (size_t)b*L_*HD + h*D_;
  float vmax = -INFINITY, vsum = 0.f;
  #pragma unroll
  for (int t=0;t<5;t++){
    int s = t*8 + grp;
    int kidx = __shfl(myidx, s, 64);
    const float* krow = kbase + (size_t)kidx*HD;
    float4 k0 = *(const float4*)(krow + l8*8);
    float4 k1 = *(const float4*)(krow + l8*8 + 4);
    float p = q0.x*k0.x + q0.y*k0.y + q0.z*k0.z + q0.w*k0.w
            + q1.x*k1.x + q1.y*k1.y + q1.z*k1.z + q1.w*k1.w;
    p += __shfl_xor(p, 1, 64);
    p += __shfl_xor(p, 2, 64);
    p += __shfl_xor(p, 4, 64);
    vmax = fmaxf(vmax, p);
    vsum += p;
  }
  vmax = fmaxf(vmax, __shfl_xor(vmax, 8, 64));
  vmax = fmaxf(vmax, __shfl_xor(vmax,16, 64));
  vmax = fmaxf(vmax, __shfl_xor(vmax,32, 64));
  vsum += __shfl_xor(vsum, 8, 64);
  vsum += __shfl_xor(vsum,16, 64);
  vsum += __shfl_xor(vsum,32, 64);
  if (lane == 0) M[bh*L_ + l] = vmax - vsum * (1.0f/(float)L_);
}

// ---------------------------------------------------------------------------
// Kernel 2: top-40 per (b,h). 256 threads: each scans 8 slots, wave-reduce,
// cross-wave combine in LDS. 40 iterations.
// ---------------------------------------------------------------------------
__global__ __launch_bounds__(256) void topk_kernel(const float* __restrict__ M,
                                                   int* __restrict__ mtop)
{
  __shared__ float mv[L_];
  __shared__ float bv[4];
  __shared__ int   bix[4];
  int bh = blockIdx.x;
  int tid = threadIdx.x, w = tid >> 6, lane = tid & 63;
  for (int i=0;i<8;i++) mv[tid + 256*i] = M[bh*L_ + tid + 256*i];
  __syncthreads();
  for (int it=0; it<U_; ++it){
    float best = -INFINITY; int bi = 0x7fffffff;
    #pragma unroll
    for (int i=0;i<8;i++){
      float vv = mv[tid + 256*i];
      if (vv > best){ best = vv; bi = tid + 256*i; }
    }
    #pragma unroll
    for (int off=32; off; off>>=1){
      float ov = __shfl_xor(best, off, 64);
      int   oi = __shfl_xor(bi,   off, 64);
      if (ov > best || (ov == best && oi < bi)){ best = ov; bi = oi; }
    }
    if (lane == 0){ bv[w] = best; bix[w] = bi; }
    __syncthreads();
    if (tid == 0){
      float bb = bv[0]; int ii = bix[0];
      #pragma unroll
      for (int j=1;j<4;j++)
        if (bv[j] > bb || (bv[j] == bb && bix[j] < ii)){ bb = bv[j]; ii = bix[j]; }
      mtop[bh*U_ + it] = ii; mv[ii] = -INFINITY;
    }
    __syncthreads();
  }
}

// ---------------------------------------------------------------------------
// Kernel 3: V column sums (for mean), atomics into vmean (memset to 0).
// ---------------------------------------------------------------------------
__global__ __launch_bounds__(256) void vmean_kernel(const float* __restrict__ v,
                                                    float* __restrict__ vmean)
{
  int g = blockIdx.x;
  int bh = g & 31, chunk = g >> 5;
  int b = bh >> 3, h = bh & 7;
  int w = threadIdx.x >> 6, lane = threadIdx.x & 63;
  int l0 = chunk*128 + w*32;
  float s = 0.f;
  for (int i=0;i<32;i++)
    s += v[(size_t)(b*L_ + l0 + i)*HD + h*D_ + lane];
  atomicAdd(&vmean[bh*D_ + lane], s);
}

// ---------------------------------------------------------------------------
// Kernel 4: out[b][l][h][:] = V_mean (sum * 1/2048), float4 stores.
// ---------------------------------------------------------------------------
__global__ __launch_bounds__(256) void init_kernel(const float* __restrict__ vmean,
                                                   float* __restrict__ out)
{
  int i = blockIdx.x*256 + threadIdx.x;
  int d4 = i & 15;
  int h  = (i >> 4) & 7;
  int bl = i >> 7;
  int b  = bl >> 11;
  float4 vm = ((const float4*)(vmean + (b*H_ + h)*D_))[d4];
  const float sc = 1.0f/(float)L_;
  float4 o; o.x = vm.x*sc; o.y = vm.y*sc; o.z = vm.z*sc; o.w = vm.w*sc;
  ((float4*)out)[i] = o;
}

// ---------------------------------------------------------------------------
// Kernel 5: attention partials. Grid = 32*KC blocks: bh = g&31, kc = g>>5.
// Block = 4 waves; ALL 40 queries resident (Qs in LDS); wave w owns queries
// w*10..w*10+9, lane owns tile keys {lane, lane+64}. nt = 16/KC tiles of 128
// keys per block, online softmax across tiles. LDS:VALU ~1:1 (r5 was ~7:1 —
// one query per wave re-read the whole K tile; 16% VALUBusy).
// psQ (p transposed for the PV phase) overlays Kt, dead after scores.
// Partial (m,l,acc[64]) per (query, kc) -> workspace, merged by combine.
// ---------------------------------------------------------------------------
__global__ __launch_bounds__(256) void attn_kernel(const float* __restrict__ q,
                                                   const float* __restrict__ k,
                                                   const float* __restrict__ v,
                                                   const int*   __restrict__ mtop,
                                                   float* __restrict__ pm,
                                                   float* __restrict__ pl,
                                                   float* __restrict__ pacc,
                                                   int nt, int KC)
{
  // Kt: 128 rows x 68 floats (pad -> (row+t)%8 bank-group spread): 34816 B
  // Vt: 128 x 64: 32768 B   Qs: 40 x 64: 10240 B   total 77824 B (2 blk/CU)
  __shared__ float sh[128*68 + 128*64 + 40*64];
  float* Kt  = sh;                 // also psQ[40][128] overlay after scores
  float* Vt  = sh + 128*68;
  float* Qs  = sh + 128*68 + 128*64;
  float* psQ = sh;

  int g  = blockIdx.x;
  int bh = g & 31, kc = g >> 5;
  int b = bh >> 3, h = bh & 7;
  int tid = threadIdx.x, w = tid >> 6, lane = tid & 63;

  // stage Q rows (40 x 64, gathered via mtop)
  #pragma unroll
  for (int c=0;c<3;c++){
    int flat = c*256 + tid;
    int row = flat >> 4, col = flat & 15;
    if (row < U_){
      int lstar = mtop[bh*U_ + row];
      ((float4*)(Qs + row*64))[col] =
        ((const float4*)(q + (size_t)(b*L_ + lstar)*HD + h*D_))[col];
    }
  }

  float m_run[10], l_run[10], acc[10], alpha[10];
  #pragma unroll
  for (int qq=0;qq<10;qq++){ m_run[qq] = -INFINITY; l_run[qq] = 0.f; acc[qq] = 0.f; }

  for (int tt=0; tt<nt; ++tt){
    int kt = (kc*nt + tt)*128;
    __syncthreads();     // Qs ready (tt=0) / prior PV reads done
    #pragma unroll
    for (int c=0;c<8;c++){
      int flat = c*256 + tid;
      int row = flat >> 4, col = flat & 15;
      ((float4*)(Kt + row*68))[col] =
        ((const float4*)(k + (size_t)(b*L_ + kt + row)*HD + h*D_))[col];
      ((float4*)(Vt + row*64))[col] =
        ((const float4*)(v + (size_t)(b*L_ + kt + row)*HD + h*D_))[col];
    }
    __syncthreads();

    // scores: 10 queries x 2 keys per lane
    float s0[10], s1[10];
    #pragma unroll
    for (int qq=0;qq<10;qq++){ s0[qq] = 0.f; s1[qq] = 0.f; }
    const float* kr0 = Kt + lane*68;
    const float* kr1 = Kt + (lane+64)*68;
    #pragma unroll
    for (int t=0;t<16;t++){
      float4 k0 = ((const float4*)kr0)[t];
      float4 k1 = ((const float4*)kr1)[t];
      #pragma unroll
      for (int qq=0;qq<10;qq++){
        float4 qf = ((const float4*)(Qs + (w*10+qq)*64))[t];
        s0[qq] += k0.x*qf.x + k0.y*qf.y + k0.z*qf.z + k0.w*qf.w;
        s1[qq] += k1.x*qf.x + k1.y*qf.y + k1.z*qf.z + k1.w*qf.w;
      }
    }
    __syncthreads();    // all waves done reading Kt before psQ overwrites it

    #pragma unroll
    for (int qq=0;qq<10;qq++){
      float a0 = s0[qq]*0.125f, a1 = s1[qq]*0.125f;
      float tmax = fmaxf(a0, a1);
      #pragma unroll
      for (int off=32; off; off>>=1) tmax = fmaxf(tmax, __shfl_xor(tmax, off, 64));
      float m_new = fmaxf(m_run[qq], tmax);
      alpha[qq] = __expf(m_run[qq] - m_new);     // tt=0: exp(-inf)=0
      float p0 = __expf(a0 - m_new);
      float p1 = __expf(a1 - m_new);
      float psum = p0 + p1;
      #pragma unroll
      for (int off=32; off; off>>=1) psum += __shfl_xor(psum, off, 64);
      l_run[qq] = l_run[qq]*alpha[qq] + psum;
      m_run[qq] = m_new;
      psQ[(w*10+qq)*128 + lane]      = p0;
      psQ[(w*10+qq)*128 + lane + 64] = p1;
    }
    __syncthreads();

    // PV: lane = output dim
    #pragma unroll
    for (int qq=0;qq<10;qq++) acc[qq] *= alpha[qq];
    for (int k4=0;k4<32;k4++){
      float v0 = Vt[(4*k4+0)*64 + lane];
      float v1 = Vt[(4*k4+1)*64 + lane];
      float v2 = Vt[(4*k4+2)*64 + lane];
      float v3 = Vt[(4*k4+3)*64 + lane];
      #pragma unroll
      for (int qq=0;qq<10;qq++){
        float4 pp = ((const float4*)(psQ + (w*10+qq)*128))[k4];
        acc[qq] += pp.x*v0 + pp.y*v1 + pp.z*v2 + pp.w*v3;
      }
    }
  }

  #pragma unroll
  for (int qq=0;qq<10;qq++){
    int pid = (bh*U_ + w*10 + qq)*KC + kc;
    pacc[(size_t)pid*64 + lane] = acc[qq];
    if (lane == 0){ pm[pid] = m_run[qq]; pl[pid] = l_run[qq]; }
  }
}

// ---------------------------------------------------------------------------
// Kernel 6: merge KC partials per (bh,u), write selected rows.
// ---------------------------------------------------------------------------
__global__ __launch_bounds__(256) void combine_kernel(const int* __restrict__ mtop,
                                                      const float* __restrict__ pm,
                                                      const float* __restrict__ pl,
                                                      const float* __restrict__ pacc,
                                                      float* __restrict__ out,
                                                      int KC)
{
  int gu = blockIdx.x*4 + (threadIdx.x >> 6);  // 0..1279
  int lane = threadIdx.x & 63;
  int bh = gu / U_, u = gu - bh*U_;
  float Mx = -INFINITY;
  for (int c=0;c<KC;c++) Mx = fmaxf(Mx, pm[gu*KC + c]);
  float Ls = 0.f, a = 0.f;
  for (int c=0;c<KC;c++){
    float e = __expf(pm[gu*KC + c] - Mx);
    Ls += pl[gu*KC + c]*e;
    a  += pacc[(size_t)(gu*KC + c)*64 + lane]*e;
  }
  int b = bh >> 3, h = bh & 7;
  int lstar = mtop[bh*U_ + u];
  out[(size_t)(b*L_ + lstar)*HD + h*D_ + lane] = a / Ls;
}

// ---------------------------------------------------------------------------
extern "C" void kernel_launch(void* const* d_in, const int* in_sizes, int n_in,
                              void* d_out, int out_size, void* d_ws, size_t ws_size,
                              hipStream_t stream)
{
  const float* q = (const float*)d_in[0];
  const float* k = (const float*)d_in[1];
  const float* v = (const float*)d_in[2];
  float* out = (float*)d_out;

  float* M     = (float*)((char*)d_ws + OFF_M);
  int*   mtop  = (int*)  ((char*)d_ws + OFF_MTOP);
  float* vmean = (float*)((char*)d_ws + OFF_VMEAN);
  float* pm    = (float*)((char*)d_ws + OFF_PM);
  float* pl    = (float*)((char*)d_ws + OFF_PL);
  float* pacc  = (float*)((char*)d_ws + OFF_PACC);

  // KC=16: 512 blocks (2/CU), needs ~5.7 MB ws; fallback KC=4 (~1.75 MB).
  int KC = (ws_size >= (size_t)WS_NEED_KC16) ? 16 : 4;
  int nt = 16 / KC;

  hipMemsetAsync(vmean, 0, 2048*sizeof(float), stream);
  m_kernel      <<<16384, 256, 0, stream>>>(q, k, M);
  topk_kernel   <<<32,    256, 0, stream>>>(M, mtop);
  vmean_kernel  <<<512,   256, 0, stream>>>(v, vmean);
  init_kernel   <<<4096,  256, 0, stream>>>(vmean, out);
  attn_kernel   <<<32*KC, 256, 0, stream>>>(q, k, v, mtop, pm, pl, pacc, nt, KC);
  combine_kernel<<<320,   256, 0, stream>>>(mtop, pm, pl, pacc, out, KC);
}